// Round 1
// baseline (311.394 us; speedup 1.0000x reference)
//
#include <hip/hip_runtime.h>
#include <hip/hip_bf16.h>
#include <stdint.h>

// Problem constants
#define B_    32
#define SW_   512
#define SL_   256
#define H_    768
#define NL_   4
#define NOUT_ 400
#define M_    (B_*SL_)   // 8192 pooled rows
#define NPAD_ 448        // N padded to 7 x 64-wide wave slices (covers 400)
#define ROWPAD_ 776      // LDS row stride in shorts (768 + 8 pad)

// B-weight tiled (MFMA fragment-linear) layout for the [448][768] bf16 matrix:
//   elem (n, k) -> ((n>>4)*(H_/8) + (k>>3))*128 + (n&15)*8 + (k&7)
// A 16x32 fragment (n-tile nt, k [k0,+32)) is the contiguous 1024B chunk at
// ((nt*96 + k0/8)*128) shorts; lane L reads 16B at +L*8 shorts.

typedef __attribute__((ext_vector_type(4))) float  f32x4;
typedef __attribute__((ext_vector_type(8))) short  bf16x8;
typedef __attribute__((ext_vector_type(4))) short  bf16x4;

__device__ __forceinline__ unsigned short f2bf(float f) {
  union { float f; unsigned int u; } x; x.f = f;
  unsigned int u = x.u;
  return (unsigned short)((u + 0x7fffu + ((u >> 16) & 1u)) >> 16);
}

// ---------------------------------------------------------------------------
// Kernel 1: cast proj_w -> bf16 fragment-linear layout (pad N to 448).
// 168 blocks x 256 threads x 8 elems = 344064 = 448*768.
// ---------------------------------------------------------------------------
__global__ __launch_bounds__(256) void wcast_kernel(
    const float* __restrict__ projw, unsigned short* __restrict__ wp) {
  const int t = threadIdx.x;
  const int base = blockIdx.x * 2048;
#pragma unroll
  for (int i = 0; i < 8; ++i) {
    int idx = base + i*256 + t;
    int n = idx / H_;
    int k = idx - n*H_;
    float v = (n < NOUT_) ? projw[n*H_ + k] : 0.0f;
    int off = ((n >> 4)*(H_/8) + (k >> 3))*128 + (n & 15)*8 + (k & 7);
    wp[off] = f2bf(v);
  }
}

// ---------------------------------------------------------------------------
// Kernel 2 (fused pool + GEMM): one block per 32 pooled rows. Grid 256,
// 448 threads (7 waves).
//  Phase 1 (restructured for MLP): wave wv pools word w = wv, wv+7, ...
//   Each lane covers 12 floats as 3 interleaved f32x4 segments
//   (float offsets 4*lane + {0,256,512}), so every global load instruction
//   is a dense 1KB wave read. The p-loop is flattened to a fixed 2-subword
//   straight-line body (actual data has len<=2): 24 independent 16B loads
//   per lane issue back-to-back. len<2 is handled by clamping addresses
//   (duplicate -> L1 hit, no extra HBM) and zeroing the weight; a generic
//   tail loop handles len>2 for robustness.
//  Phase 2: wave w computes out[32 x 64] for N slice [w*64,+64):
//   A-frags ds_read_b128 from LDS (2-way bank aliasing = free), B-frags
//   bf16x8 from wp (L2-resident), MFMA 16x16x32 bf16, depth-2 K-pipeline.
// ---------------------------------------------------------------------------
__global__ __launch_bounds__(448) void fused_kernel(
    const int* __restrict__ lens,
    const float* __restrict__ hidden,
    const float* __restrict__ mixw,
    const float* __restrict__ gamma,
    const unsigned short* __restrict__ wp,
    float* __restrict__ out) {
  const int t  = threadIdx.x;        // 0..447
  const int rt = blockIdx.x;         // 0..255 (32-row tile)
  const int b  = rt >> 3;            // example
  const int j0 = (rt & 7) << 5;      // first of 32 words, <= 224
  const int* lrow = lens + b * SL_;
  const int lane = t & 63;
  const int wv = t >> 6;             // 0..6

  __shared__ int s_start[32];
  __shared__ int s_len[32];
  __shared__ int s_wred[7];
  __shared__ __align__(16) unsigned short s_tile[32][ROWPAD_];

  // prefix = sum(lens[b, 0..j0)), j0 <= 224 < 448
  int partial = (t < j0) ? lrow[t] : 0;
#pragma unroll
  for (int off = 32; off > 0; off >>= 1)
    partial += __shfl_down(partial, off);
  if (lane == 0) s_wred[wv] = partial;
  if (t < 32) s_len[t] = lrow[j0 + t];
  __syncthreads();
  if (t == 0) {
    int s = s_wred[0] + s_wred[1] + s_wred[2] + s_wred[3] + s_wred[4] +
            s_wred[5] + s_wred[6];
#pragma unroll
    for (int w = 0; w < 32; ++w) { s_start[w] = s; s += s_len[w]; }
  }

  // softmax over 4 mix weights (all-thread redundant, trivial)
  float w0 = mixw[0], w1 = mixw[1], w2 = mixw[2], w3 = mixw[3];
  float mx = fmaxf(fmaxf(w0, w1), fmaxf(w2, w3));
  float ew[NL_];
  ew[0] = __expf(w0 - mx); ew[1] = __expf(w1 - mx);
  ew[2] = __expf(w2 - mx); ew[3] = __expf(w3 - mx);
  float esum = ew[0] + ew[1] + ew[2] + ew[3];
  const float gsc = gamma[0] / esum;
  __syncthreads();

  // ---- Phase 1: wave-per-word ragged mean pool with straight-line loads.
  const size_t bbase = (size_t)b * (SW_ * H_);
  for (int w = wv; w < 32; w += 7) {
    const int len = s_len[w];
    const int st  = s_start[w];
    int q0 = st;                 if (q0 > SW_ - 1) q0 = SW_ - 1;
    int q1 = (len >= 2) ? st + 1 : q0;
    if (q1 > SW_ - 1) q1 = SW_ - 1;
    const float fa = (len >= 1) ? 1.0f : 0.0f;
    const float fb = (len >= 2) ? 1.0f : 0.0f;

    f32x4 a0 = {0.0f, 0.0f, 0.0f, 0.0f};
    f32x4 a1 = {0.0f, 0.0f, 0.0f, 0.0f};
    f32x4 a2 = {0.0f, 0.0f, 0.0f, 0.0f};
#pragma unroll
    for (int l = 0; l < NL_; ++l) {
      const f32x4* v0 = reinterpret_cast<const f32x4*>(
          hidden + (size_t)l * (B_ * SW_ * H_) + bbase + (size_t)q0 * H_);
      const f32x4* v1 = reinterpret_cast<const f32x4*>(
          hidden + (size_t)l * (B_ * SW_ * H_) + bbase + (size_t)q1 * H_);
      const float wa = ew[l] * fa;
      const float wb = ew[l] * fb;
      a0 += v0[lane]       * wa;
      a1 += v0[lane +  64] * wa;
      a2 += v0[lane + 128] * wa;
      a0 += v1[lane]       * wb;
      a1 += v1[lane +  64] * wb;
      a2 += v1[lane + 128] * wb;
    }
    // generic tail for len > 2 (never taken for this data distribution)
    for (int p = 2; p < len; ++p) {
      int q = st + p; if (q > SW_ - 1) q = SW_ - 1;
#pragma unroll
      for (int l = 0; l < NL_; ++l) {
        const f32x4* v = reinterpret_cast<const f32x4*>(
            hidden + (size_t)l * (B_ * SW_ * H_) + bbase + (size_t)q * H_);
        a0 += v[lane]       * ew[l];
        a1 += v[lane +  64] * ew[l];
        a2 += v[lane + 128] * ew[l];
      }
    }
    const float sc = gsc / (float)((len > 0) ? len : 1);
    bf16x4 o0, o1, o2;
#pragma unroll
    for (int i = 0; i < 4; ++i) {
      o0[i] = (short)f2bf(a0[i] * sc);
      o1[i] = (short)f2bf(a1[i] * sc);
      o2[i] = (short)f2bf(a2[i] * sc);
    }
    *reinterpret_cast<bf16x4*>(&s_tile[w][lane * 4])       = o0;
    *reinterpret_cast<bf16x4*>(&s_tile[w][256 + lane * 4]) = o1;
    *reinterpret_cast<bf16x4*>(&s_tile[w][512 + lane * 4]) = o2;
  }
  __syncthreads();

  // ---- Phase 2: GEMM. Wave w -> N slice [w*64, +64): 2 m-tiles x 4 n-tiles.
  const int nbase = wv * 64;
  const int nt0 = wv * 4;            // B chunk-row base

  f32x4 acc[2][4];
#pragma unroll
  for (int i = 0; i < 2; ++i)
#pragma unroll
    for (int j = 0; j < 4; ++j)
      acc[i][j] = (f32x4){0.0f, 0.0f, 0.0f, 0.0f};

  // A fragment: lane L -> A[m = mt*16 + (L&15)][k = k0 + (L>>4)*8 .. +8]
#define LDA(k0, mt) \
  (*reinterpret_cast<const bf16x8*>(&s_tile[(mt)*16 + (lane & 15)][(k0) + (lane >> 4)*8]))
#define LDB(k0, nt) \
  (*reinterpret_cast<const bf16x8*>(wp + ((size_t)((nt0 + (nt))*(H_/8) + ((k0) >> 3)))*128 + lane*8))

  bf16x8 aP[2], bP[4], aQ[2], bQ[4];
#pragma unroll
  for (int i = 0; i < 2; ++i) aP[i] = LDA(0, i);
#pragma unroll
  for (int i = 0; i < 4; ++i) bP[i] = LDB(0, i);
#pragma unroll
  for (int i = 0; i < 2; ++i) aQ[i] = LDA(32, i);
#pragma unroll
  for (int i = 0; i < 4; ++i) bQ[i] = LDB(32, i);

  for (int k0 = 64; k0 < H_; k0 += 64) {
#pragma unroll
    for (int mt = 0; mt < 2; ++mt)
#pragma unroll
      for (int nt = 0; nt < 4; ++nt)
        acc[mt][nt] = __builtin_amdgcn_mfma_f32_16x16x32_bf16(aP[mt], bP[nt], acc[mt][nt], 0, 0, 0);
#pragma unroll
    for (int i = 0; i < 2; ++i) aP[i] = LDA(k0, i);
#pragma unroll
    for (int i = 0; i < 4; ++i) bP[i] = LDB(k0, i);
#pragma unroll
    for (int mt = 0; mt < 2; ++mt)
#pragma unroll
      for (int nt = 0; nt < 4; ++nt)
        acc[mt][nt] = __builtin_amdgcn_mfma_f32_16x16x32_bf16(aQ[mt], bQ[nt], acc[mt][nt], 0, 0, 0);
#pragma unroll
    for (int i = 0; i < 2; ++i) aQ[i] = LDA(k0 + 32, i);
#pragma unroll
    for (int i = 0; i < 4; ++i) bQ[i] = LDB(k0 + 32, i);
  }
#pragma unroll
  for (int mt = 0; mt < 2; ++mt)
#pragma unroll
    for (int nt = 0; nt < 4; ++nt) {
      acc[mt][nt] = __builtin_amdgcn_mfma_f32_16x16x32_bf16(aP[mt], bP[nt], acc[mt][nt], 0, 0, 0);
      acc[mt][nt] = __builtin_amdgcn_mfma_f32_16x16x32_bf16(aQ[mt], bQ[nt], acc[mt][nt], 0, 0, 0);
    }
#undef LDA
#undef LDB

  // C/D layout: row = (lane>>4)*4 + r, col = lane&15
  const int r0 = (lane >> 4) * 4;
  const int c = lane & 15;
#pragma unroll
  for (int mt = 0; mt < 2; ++mt) {
#pragma unroll
    for (int nt = 0; nt < 4; ++nt) {
      int n = nbase + nt*16 + c;
      if (n < NOUT_) {
        int mrow = rt*32 + mt*16 + r0;
#pragma unroll
        for (int r = 0; r < 4; ++r)
          out[(size_t)(mrow + r)*NOUT_ + n] = acc[mt][nt][r];
      }
    }
  }
}

// ---------------------------------------------------------------------------
extern "C" void kernel_launch(void* const* d_in, const int* in_sizes, int n_in,
                              void* d_out, int out_size, void* d_ws, size_t ws_size,
                              hipStream_t stream) {
  // setup_inputs order: subwords, bert_lens, bert_mask, hidden_states,
  //                     mix_weights, gamma, proj_w
  const int*   lens   = (const int*)d_in[1];
  const float* hidden = (const float*)d_in[3];
  const float* mixw   = (const float*)d_in[4];
  const float* gamma  = (const float*)d_in[5];
  const float* projw  = (const float*)d_in[6];
  float* out = (float*)d_out;

  unsigned short* wp = (unsigned short*)d_ws;   // 448*768*2 = 688128 B

  wcast_kernel<<<dim3(168), dim3(256), 0, stream>>>(projw, wp);
  fused_kernel<<<dim3(256), dim3(448), 0, stream>>>(
      lens, hidden, mixw, gamma, wp, out);
}

// Round 2
// 279.477 us; speedup vs baseline: 1.1142x; 1.1142x over previous
//
#include <hip/hip_runtime.h>
#include <hip/hip_bf16.h>
#include <stdint.h>

// Problem constants
#define B_    32
#define SW_   512
#define SL_   256
#define H_    768
#define NL_   4
#define NOUT_ 400
#define M_    (B_*SL_)   // 8192 pooled rows
#define NPAD_ 448        // N padded to 7 x 64-wide wave slices (covers 400)
#define ROWPAD_ 776      // LDS row stride in shorts (768 + 8 pad)

// B-weight tiled (MFMA fragment-linear) layout for the [448][768] bf16 matrix:
//   elem (n, k) -> ((n>>4)*(H_/8) + (k>>3))*128 + (n&15)*8 + (k&7)
// A 16x32 fragment (n-tile nt, k [k0,+32)) is the contiguous 1024B chunk at
// ((nt*96 + k0/8)*128) shorts; lane L reads 16B at +L*8 shorts.

typedef __attribute__((ext_vector_type(4))) float  f32x4;
typedef __attribute__((ext_vector_type(8))) short  bf16x8;
typedef __attribute__((ext_vector_type(4))) short  bf16x4;

__device__ __forceinline__ unsigned short f2bf(float f) {
  union { float f; unsigned int u; } x; x.f = f;
  unsigned int u = x.u;
  return (unsigned short)((u + 0x7fffu + ((u >> 16) & 1u)) >> 16);
}

// ---------------------------------------------------------------------------
// Kernel 1: cast proj_w -> bf16 fragment-linear layout (pad N to 448).
// 168 blocks x 256 threads x 8 elems = 344064 = 448*768.
// ---------------------------------------------------------------------------
__global__ __launch_bounds__(256) void wcast_kernel(
    const float* __restrict__ projw, unsigned short* __restrict__ wp) {
  const int t = threadIdx.x;
  const int base = blockIdx.x * 2048;
#pragma unroll
  for (int i = 0; i < 8; ++i) {
    int idx = base + i*256 + t;
    int n = idx / H_;
    int k = idx - n*H_;
    float v = (n < NOUT_) ? projw[n*H_ + k] : 0.0f;
    int off = ((n >> 4)*(H_/8) + (k >> 3))*128 + (n & 15)*8 + (k & 7);
    wp[off] = f2bf(v);
  }
}

// ---------------------------------------------------------------------------
// Kernel 2 (fused pool + GEMM): one block per 32 pooled rows. Grid 256,
// 448 threads (7 waves).
//  Phase 1: word starts via block reduce + 32-wide serial scan; softmax mix
//   + gamma + ragged mean into a padded row-major LDS tile (48.5 KB).
//   Structure: two 192-thread groups (3 waves each); group g does word
//   w = 2*it + g; thread u covers floats 4u..4u+3. The p-loop is flattened
//   to a straight-line 2-subword body (data has len<=2) guarded by a
//   wave-uniform if(len): len==0 issues NO loads; len==1 duplicates the
//   q0 load (back-to-back same address -> L1 hit) with zero weight. 8
//   independent 16B loads in flight per thread per word (x2 via unroll 2).
//   Generic tail loop for len>2 kept for robustness.
//  Phase 2: wave w computes out[32 x 64] for N slice [w*64,+64):
//   A-frags ds_read_b128 from LDS (2-way bank aliasing = free), B-frags
//   bf16x8 from wp (L2-resident), MFMA 16x16x32 bf16, depth-2 K-pipeline.
// ---------------------------------------------------------------------------
__global__ __launch_bounds__(448) void fused_kernel(
    const int* __restrict__ lens,
    const float* __restrict__ hidden,
    const float* __restrict__ mixw,
    const float* __restrict__ gamma,
    const unsigned short* __restrict__ wp,
    float* __restrict__ out) {
  const int t  = threadIdx.x;        // 0..447
  const int rt = blockIdx.x;         // 0..255 (32-row tile)
  const int b  = rt >> 3;            // example
  const int j0 = (rt & 7) << 5;      // first of 32 words, <= 224
  const int* lrow = lens + b * SL_;

  __shared__ int s_start[32];
  __shared__ int s_len[32];
  __shared__ int s_wred[7];
  __shared__ __align__(16) unsigned short s_tile[32][ROWPAD_];

  // prefix = sum(lens[b, 0..j0)), j0 <= 224 < 448
  int partial = (t < j0) ? lrow[t] : 0;
#pragma unroll
  for (int off = 32; off > 0; off >>= 1)
    partial += __shfl_down(partial, off);
  if ((t & 63) == 0) s_wred[t >> 6] = partial;
  if (t < 32) s_len[t] = lrow[j0 + t];
  __syncthreads();
  if (t == 0) {
    int s = s_wred[0] + s_wred[1] + s_wred[2] + s_wred[3] + s_wred[4] +
            s_wred[5] + s_wred[6];
#pragma unroll
    for (int w = 0; w < 32; ++w) { s_start[w] = s; s += s_len[w]; }
  }

  // softmax over 4 mix weights (all-thread redundant, trivial)
  float w0 = mixw[0], w1 = mixw[1], w2 = mixw[2], w3 = mixw[3];
  float mx = fmaxf(fmaxf(w0, w1), fmaxf(w2, w3));
  float ew[NL_];
  ew[0] = __expf(w0 - mx); ew[1] = __expf(w1 - mx);
  ew[2] = __expf(w2 - mx); ew[3] = __expf(w3 - mx);
  float esum = ew[0] + ew[1] + ew[2] + ew[3];
  const float gsc = gamma[0] / esum;
  __syncthreads();

  // ---- Phase 1: pool 32 words. Two 192-thread groups; group g does word
  // w = 2*it + g; thread u covers floats 4u..4u+3 of the 768. 16 iters.
  if (t < 384) {
    const int g = t / 192;
    const int u = t - g * 192;
#pragma unroll 2
    for (int it = 0; it < 16; ++it) {
      const int w = it*2 + g;
      const int len = s_len[w];
      const int st  = s_start[w];
      f32x4 acc = {0.0f, 0.0f, 0.0f, 0.0f};
      if (len) {                       // wave-uniform: group = 3 whole waves
        const int q1 = (len >= 2) ? st + 1 : st;   // len==1: dup -> L1 hit
        const float fb = (len >= 2) ? 1.0f : 0.0f;
#pragma unroll
        for (int l = 0; l < NL_; ++l) {
          const float* base = hidden + (size_t)(l*B_ + b) * (SW_ * (size_t)H_);
          const f32x4* v0 = reinterpret_cast<const f32x4*>(base + (size_t)st * H_);
          const f32x4* v1 = reinterpret_cast<const f32x4*>(base + (size_t)q1 * H_);
          acc += v0[u] * ew[l];
          acc += v1[u] * (ew[l] * fb);
        }
        // generic tail for len > 2 (never taken for this data distribution)
        for (int p = 2; p < len; ++p) {
#pragma unroll
          for (int l = 0; l < NL_; ++l) {
            const f32x4* src = reinterpret_cast<const f32x4*>(
                hidden + ((size_t)(l*B_ + b)*SW_ + (size_t)(st + p)) * H_);
            acc += src[u] * ew[l];
          }
        }
      }
      const float sc = gsc / (float)((len > 0) ? len : 1);
      bf16x4 o;
      o[0] = (short)f2bf(acc[0] * sc);
      o[1] = (short)f2bf(acc[1] * sc);
      o[2] = (short)f2bf(acc[2] * sc);
      o[3] = (short)f2bf(acc[3] * sc);
      *reinterpret_cast<bf16x4*>(&s_tile[w][u*4]) = o;
    }
  }
  __syncthreads();

  // ---- Phase 2: GEMM. Wave w -> N slice [w*64, +64): 2 m-tiles x 4 n-tiles.
  const int lane = t & 63;
  const int wv = t >> 6;             // 0..6
  const int nbase = wv * 64;
  const int nt0 = wv * 4;            // B chunk-row base

  f32x4 acc[2][4];
#pragma unroll
  for (int i = 0; i < 2; ++i)
#pragma unroll
    for (int j = 0; j < 4; ++j)
      acc[i][j] = (f32x4){0.0f, 0.0f, 0.0f, 0.0f};

  // A fragment: lane L -> A[m = mt*16 + (L&15)][k = k0 + (L>>4)*8 .. +8]
#define LDA(k0, mt) \
  (*reinterpret_cast<const bf16x8*>(&s_tile[(mt)*16 + (lane & 15)][(k0) + (lane >> 4)*8]))
#define LDB(k0, nt) \
  (*reinterpret_cast<const bf16x8*>(wp + ((size_t)((nt0 + (nt))*(H_/8) + ((k0) >> 3)))*128 + lane*8))

  bf16x8 aP[2], bP[4], aQ[2], bQ[4];
#pragma unroll
  for (int i = 0; i < 2; ++i) aP[i] = LDA(0, i);
#pragma unroll
  for (int i = 0; i < 4; ++i) bP[i] = LDB(0, i);
#pragma unroll
  for (int i = 0; i < 2; ++i) aQ[i] = LDA(32, i);
#pragma unroll
  for (int i = 0; i < 4; ++i) bQ[i] = LDB(32, i);

  for (int k0 = 64; k0 < H_; k0 += 64) {
#pragma unroll
    for (int mt = 0; mt < 2; ++mt)
#pragma unroll
      for (int nt = 0; nt < 4; ++nt)
        acc[mt][nt] = __builtin_amdgcn_mfma_f32_16x16x32_bf16(aP[mt], bP[nt], acc[mt][nt], 0, 0, 0);
#pragma unroll
    for (int i = 0; i < 2; ++i) aP[i] = LDA(k0, i);
#pragma unroll
    for (int i = 0; i < 4; ++i) bP[i] = LDB(k0, i);
#pragma unroll
    for (int mt = 0; mt < 2; ++mt)
#pragma unroll
      for (int nt = 0; nt < 4; ++nt)
        acc[mt][nt] = __builtin_amdgcn_mfma_f32_16x16x32_bf16(aQ[mt], bQ[nt], acc[mt][nt], 0, 0, 0);
#pragma unroll
    for (int i = 0; i < 2; ++i) aQ[i] = LDA(k0 + 32, i);
#pragma unroll
    for (int i = 0; i < 4; ++i) bQ[i] = LDB(k0 + 32, i);
  }
#pragma unroll
  for (int mt = 0; mt < 2; ++mt)
#pragma unroll
    for (int nt = 0; nt < 4; ++nt) {
      acc[mt][nt] = __builtin_amdgcn_mfma_f32_16x16x32_bf16(aP[mt], bP[nt], acc[mt][nt], 0, 0, 0);
      acc[mt][nt] = __builtin_amdgcn_mfma_f32_16x16x32_bf16(aQ[mt], bQ[nt], acc[mt][nt], 0, 0, 0);
    }
#undef LDA
#undef LDB

  // C/D layout: row = (lane>>4)*4 + r, col = lane&15
  const int r0 = (lane >> 4) * 4;
  const int c = lane & 15;
#pragma unroll
  for (int mt = 0; mt < 2; ++mt) {
#pragma unroll
    for (int nt = 0; nt < 4; ++nt) {
      int n = nbase + nt*16 + c;
      if (n < NOUT_) {
        int mrow = rt*32 + mt*16 + r0;
#pragma unroll
        for (int r = 0; r < 4; ++r)
          out[(size_t)(mrow + r)*NOUT_ + n] = acc[mt][nt][r];
      }
    }
  }
}

// ---------------------------------------------------------------------------
extern "C" void kernel_launch(void* const* d_in, const int* in_sizes, int n_in,
                              void* d_out, int out_size, void* d_ws, size_t ws_size,
                              hipStream_t stream) {
  // setup_inputs order: subwords, bert_lens, bert_mask, hidden_states,
  //                     mix_weights, gamma, proj_w
  const int*   lens   = (const int*)d_in[1];
  const float* hidden = (const float*)d_in[3];
  const float* mixw   = (const float*)d_in[4];
  const float* gamma  = (const float*)d_in[5];
  const float* projw  = (const float*)d_in[6];
  float* out = (float*)d_out;

  unsigned short* wp = (unsigned short*)d_ws;   // 448*768*2 = 688128 B

  wcast_kernel<<<dim3(168), dim3(256), 0, stream>>>(projw, wp);
  fused_kernel<<<dim3(256), dim3(448), 0, stream>>>(
      lens, hidden, mixw, gamma, wp, out);
}